// Round 4
// baseline (553.079 us; speedup 1.0000x reference)
//
#include <hip/hip_runtime.h>
#include <math.h>

// ---------------------------------------------------------------------------
// CapsNet forward on MI355X.
// R15b: resubmit of R15 (round-3 bench was an infra "container failed twice";
//      kernel re-audited: bounds, barriers, fragment mappings all verified).
//      conv2 switched 16x16x32 -> 32x32x16 MFMA (2075 -> 2495 TF ceiling,
//      floor 147 -> 122us; instr count halves, B bytes/FLOP halve).
//      Blocks now 8 images (M=288=9x32), 512 thr / 8 waves, wave = 9 Mtiles
//      x one 32-col N slice. Slab 2x57KB, 1 block/CU (8 waves/CU, same as
//      before). whi/wlo [tap][icgG][oc][ic] layout unchanged (lane>>5 picks
//      tap within pair). conv1 slab base now 8-img groups.
// ---------------------------------------------------------------------------

typedef float floatx4 __attribute__((ext_vector_type(4)));
typedef float floatx16 __attribute__((ext_vector_type(16)));
typedef __bf16 bf16x8 __attribute__((ext_vector_type(8)));
typedef unsigned uintx4 __attribute__((ext_vector_type(4)));

#define XHI_OFF 0u
#define XLO_OFF 58720256u           // 32*32*28672 shorts = 58720256 B
#define WHI_OFF 117440512u
#define WLO_OFF 128974848u
#define Y2_OFF  140509184u
#define VP_OFF  0u                  // overlaps xhi: dead once conv2 is done
#define Y2_BYTES 9437184u

// slab geometry (shorts): iy stride 88, img stride 1760; 8-img slab:
// parity offset 14144 (8*1760+64 pad), slab stride 28672 (57344 B = 56 chunks)
#define SL_IY   88
#define SL_IMG  1760
#define SL_PAR  14144
#define SL_STRIDE 28672

#define TAPSTRIDE 65536             // shorts per tap in w layout

__device__ __forceinline__ void bf16split(float v, short& hs, short& ls) {
  unsigned u = __builtin_bit_cast(unsigned, v);
  unsigned r = (u + 0x7FFFu + ((u >> 16) & 1u)) & 0xFFFF0000u;
  hs = (short)(r >> 16);
  float lo = v - __builtin_bit_cast(float, r);
  unsigned u2 = __builtin_bit_cast(unsigned, lo);
  unsigned r2 = u2 + 0x7FFFu + ((u2 >> 16) & 1u);
  ls = (short)(r2 >> 16);
}

// async 7x1024B wave-linear global->LDS copy (lane gives +16B each)
__device__ __forceinline__ void stage7(const short* gp, short* lp) {
#pragma unroll
  for (int c = 0; c < 7; c++)
    __builtin_amdgcn_global_load_lds(
        (const __attribute__((address_space(1))) void*)(gp + c * 512),
        (__attribute__((address_space(3))) void*)(lp + c * 512), 16, 0, 0);
}

// ============================ conv1: 9x9 s1 + ReLU ==========================
__global__ __launch_bounds__(320) void conv1_k(
    const float* __restrict__ inp, const float* __restrict__ W1,
    const float* __restrict__ b1, short* __restrict__ xhi,
    short* __restrict__ xlo) {
  __shared__ __align__(16) float img[784];
  __shared__ float wl[81 * 34];
  const int blk = blockIdx.x;
  const int b = blk >> 3;
  const int cbase = (blk & 7) * 32;
  const int t = threadIdx.x;

  const float4* src = (const float4*)(inp + b * 784);
  for (int idx = t; idx < 196; idx += 320) ((float4*)img)[idx] = src[idx];
  for (int idx = t; idx < 2592; idx += 320) {
    int c = idx / 81, tap = idx - c * 81;
    wl[tap * 34 + c] = W1[(cbase + c) * 81 + tap];
  }
  __syncthreads();

  const int oy = t >> 4;
  const int ct = t & 15;
  const int c0 = cbase + ct * 2;
  const float bias0 = b1[c0], bias1 = b1[c0 + 1];
  float acc0[20], acc1[20];
#pragma unroll
  for (int ox = 0; ox < 20; ox++) { acc0[ox] = bias0; acc1[ox] = bias1; }

#pragma unroll 1
  for (int i = 0; i < 9; i++) {
    float wr0[9], wr1[9];
#pragma unroll
    for (int j = 0; j < 9; j++) {
      float2 wv = *(const float2*)&wl[(i * 9 + j) * 34 + ct * 2];
      wr0[j] = wv.x; wr1[j] = wv.y;
    }
    float xr[28];
    const float4* rp = (const float4*)&img[(oy + i) * 28];
#pragma unroll
    for (int k = 0; k < 7; k++) {
      float4 v = rp[k];
      xr[4 * k] = v.x; xr[4 * k + 1] = v.y; xr[4 * k + 2] = v.z; xr[4 * k + 3] = v.w;
    }
#pragma unroll
    for (int j = 0; j < 9; j++)
#pragma unroll
      for (int ox = 0; ox < 20; ox++) {
        acc0[ox] = fmaf(xr[ox + j], wr0[j], acc0[ox]);
        acc1[ox] = fmaf(xr[ox + j], wr1[j], acc1[ox]);
      }
  }

  // write directly in conv2's 8-image slab layout:
  // slab id = icgG*32 + (b>>3); within: (ox&1)*SL_PAR + (b&7)*SL_IMG
  //                                     + oy*SL_IY + (ox>>1)*8 + ic
  const int icgG = c0 >> 3;
  const long sbase = ((long)(icgG * 32 + (b >> 3))) * SL_STRIDE
                   + (long)(b & 7) * SL_IMG + (long)oy * SL_IY + (c0 & 7);
#pragma unroll
  for (int ox = 0; ox < 20; ox++) {
    float v0 = fmaxf(acc0[ox], 0.f), v1 = fmaxf(acc1[ox], 0.f);
    short h0, l0, h1, l1;
    bf16split(v0, h0, l0);
    bf16split(v1, h1, l1);
    long a = sbase + (ox & 1) * SL_PAR + (ox >> 1) * 8;
    *(short2*)&xhi[a] = make_short2(h0, h1);
    *(short2*)&xlo[a] = make_short2(l0, l1);
  }
  // zero the row pads so lines are fully written
  {
    long a0 = sbase + 80;
    *(short2*)&xhi[a0] = make_short2(0, 0);
    *(short2*)&xlo[a0] = make_short2(0, 0);
    long a1 = sbase + SL_PAR + 80;
    *(short2*)&xhi[a1] = make_short2(0, 0);
    *(short2*)&xlo[a1] = make_short2(0, 0);
  }
}

// ======= W2 transform (coalesced LDS transpose) =============================
// layout out: [tap][icgG(32)][oc(256)][ic(8)], taps 81..87 zeroed.
__global__ __launch_bounds__(256) void wtrans_k(
    const float* __restrict__ W2, short* __restrict__ whi,
    short* __restrict__ wlo) {
  __shared__ short lh[81 * 258];
  __shared__ short ll[81 * 258];
  const int blk = blockIdx.x;
  const int icg = blk & 31, ocg = blk >> 5;
  const int t = threadIdx.x;

  for (int idx = t; idx < 20736; idx += 256) {
    int c = idx / 648, r = idx - c * 648;      // c = oc_local, r = ics*81+tap
    int ics = r / 81, tap = r - ics * 81;
    float v = W2[(long)(ocg * 32 + c) * 20736 + icg * 648 + r];
    short h, l;
    bf16split(v, h, l);
    lh[tap * 258 + c * 8 + ics] = h;
    ll[tap * 258 + c * 8 + ics] = l;
  }
  __syncthreads();
  const long obase = (long)icg * 2048 + ocg * 256 + t;
#pragma unroll 1
  for (int tap = 0; tap < 88; tap++) {
    short h = 0, l = 0;
    if (tap < 81) { h = lh[tap * 258 + t]; l = ll[tap * 258 + t]; }
    whi[obase + (long)tap * TAPSTRIDE] = h;
    wlo[obase + (long)tap * TAPSTRIDE] = l;
  }
}

// ================= conv2: MFMA bf16-split implicit GEMM (32x32x16) ==========
// grid 256 (1 block/CU): ks = blk&7, mb = blk>>3 (8 images). M288 x N256;
// 8 waves, each wave = 9 Mtiles(32) x one 32-col N slice. Double-buffered
// 57KB slabs staged via global_load_lds. K-step = tap pair (K=16):
// lane>>5 selects tap within pair for both A and B fragments.
__global__ __launch_bounds__(512, 2) void conv2_k(
    const short* __restrict__ xhi, const short* __restrict__ xlo,
    const short* __restrict__ whi, const short* __restrict__ wlo,
    float* __restrict__ y2) {
  __shared__ __align__(16) short slab[2][SL_STRIDE];   // 2 x 57344 B

  const int blk = blockIdx.x;
  const int ks = blk & 7;
  const int mb = blk >> 3;
  const int t = threadIdx.x;
  const int lane = t & 63;
  const int l31 = lane & 31;
  const int h = lane >> 5;           // tap-within-pair select
  const int wv = t >> 6;             // 0..7

  int combo[9];
#pragma unroll
  for (int mt = 0; mt < 9; mt++) {
    int row = mt * 32 + l31;         // 0..287
    int im = row / 36;
    int pos = row - im * 36;
    int oy = pos / 6, ox = pos - oy * 6;
    combo[mt] = im * SL_IMG + oy * (2 * SL_IY) + ox * 8;
  }

  floatx16 acc[9];
#pragma unroll
  for (int mt = 0; mt < 9; mt++) acc[mt] = (floatx16)0.f;

  // per-wave staging offset: 7 chunks of 1024B, lane-linear
  const int stoff = wv * 7 * 512 + lane * 8;

  // prologue: stage hi(icg=0) into slab[0]
  stage7(xhi + (long)(ks * 4 * 32 + mb) * SL_STRIDE + stoff, &slab[0][stoff]);

#pragma unroll 1
  for (int icg = 0; icg < 4; icg++) {
    const int icgG = ks * 4 + icg;
    // B base: [tap = h][icgG][oc = wv*32 + l31][ic]
    const long wb = (long)icgG * 2048 + (wv * 32 + l31) * 8 + (long)h * TAPSTRIDE;

    __syncthreads();   // drains vmcnt: hi slab ready; all waves done with slab[1]
    // issue lo(icg) -> slab[1], hides under HI compute
    stage7(xlo + (long)(icgG * 32 + mb) * SL_STRIDE + stoff, &slab[1][stoff]);

    // ---------------- HI phase: A_hi * (B_hi + B_lo) ----------------
    {
      bf16x8 cbh = *(const bf16x8*)&whi[wb];
#pragma unroll 1
      for (int kst = 0; kst < 42; kst++) {
        bf16x8 nbh = *(const bf16x8*)&whi[wb + (long)(2 * kst + 2) * TAPSTRIDE];
        bf16x8 cbl = *(const bf16x8*)&wlo[wb + (long)(2 * kst) * TAPSTRIDE];
        const int tap = 2 * kst + h;
        const int i = tap / 9, j = tap - i * 9;
        const int aoff = (j & 1) * SL_PAR + i * SL_IY + (j >> 1) * 8;
        bf16x8 av[9];
#pragma unroll
        for (int mt = 0; mt < 9; mt++)
          av[mt] = *(const bf16x8*)&slab[0][aoff + combo[mt]];
#pragma unroll
        for (int mt = 0; mt < 9; mt++)
          acc[mt] = __builtin_amdgcn_mfma_f32_32x32x16_bf16(av[mt], cbh, acc[mt], 0, 0, 0);
#pragma unroll
        for (int mt = 0; mt < 9; mt++)
          acc[mt] = __builtin_amdgcn_mfma_f32_32x32x16_bf16(av[mt], cbl, acc[mt], 0, 0, 0);
        cbh = nbh;
      }
    }

    __syncthreads();   // drains vmcnt: lo slab ready; all waves done with slab[0]
    if (icg < 3)       // issue hi(icg+1) -> slab[0], hides under LO compute
      stage7(xhi + (long)((icgG + 1) * 32 + mb) * SL_STRIDE + stoff, &slab[0][stoff]);

    // ---------------- LO phase: A_lo * B_hi ----------------
    {
      bf16x8 cbh = *(const bf16x8*)&whi[wb];
#pragma unroll 1
      for (int kst = 0; kst < 42; kst++) {
        bf16x8 nbh = *(const bf16x8*)&whi[wb + (long)(2 * kst + 2) * TAPSTRIDE];
        const int tap = 2 * kst + h;
        const int i = tap / 9, j = tap - i * 9;
        const int aoff = (j & 1) * SL_PAR + i * SL_IY + (j >> 1) * 8;
        bf16x8 av[9];
#pragma unroll
        for (int mt = 0; mt < 9; mt++)
          av[mt] = *(const bf16x8*)&slab[1][aoff + combo[mt]];
#pragma unroll
        for (int mt = 0; mt < 9; mt++)
          acc[mt] = __builtin_amdgcn_mfma_f32_32x32x16_bf16(av[mt], cbh, acc[mt], 0, 0, 0);
        cbh = nbh;
      }
    }
  }

  // epilogue: 32x32 C/D layout col=lane&31, row=(reg&3)+8*(reg>>2)+4*(lane>>5)
  const int oc = wv * 32 + l31;
#pragma unroll
  for (int mt = 0; mt < 9; mt++) {
    const int rowb = mb * 288 + mt * 32 + 4 * h;
#pragma unroll
    for (int r = 0; r < 16; r++) {
      int row = rowb + (r & 3) + 8 * (r >> 2);
      atomicAdd(&y2[(long)row * 256 + oc], acc[mt][r]);
    }
  }
}

// ================= primary caps squash + predictions + routing ==============
__global__ __launch_bounds__(256) void caps_k(
    const float* __restrict__ y2, const float* __restrict__ b2,
    const float* __restrict__ Wcaps, const float* __restrict__ b_route,
    float* __restrict__ vpart) {
  __shared__ float u[288];
  __shared__ float usc[36];
  __shared__ float up[5760];
  __shared__ float bl[360];
  __shared__ float cl[360];
  __shared__ float sv[160];
  __shared__ float vv[160];
  __shared__ float scale[10];
  const int blk = blockIdx.x;
  const int g = blk & 31, b = blk >> 5;
  const int t = threadIdx.x;

  for (int idx = t; idx < 288; idx += 256) {
    int s = idx >> 3, d = idx & 7;
    u[idx] = y2[((long)b * 36 + s) * 256 + g * 8 + d] + b2[g * 8 + d];
  }
  for (int idx = t; idx < 360; idx += 256) bl[idx] = b_route[g * 360 + idx];
  __syncthreads();
  if (t < 36) {
    float l2 = 0.f;
#pragma unroll
    for (int d = 0; d < 8; d++) { float v = u[t * 8 + d]; l2 = fmaf(v, v, l2); }
    float l = sqrtf(l2);
    usc[t] = (l2 / (1.f + l2)) / (l + 1e-8f);
  }
  __syncthreads();
  for (int idx = t; idx < 288; idx += 256) u[idx] *= usc[idx >> 3];
  __syncthreads();
  for (int idx = t; idx < 5760; idx += 256) {
    int s = idx / 160, k = idx - s * 160;
    const float* wp = Wcaps + (g * 36 + s) * 8 * 160 + k;
    float a = 0.f;
#pragma unroll
    for (int d = 0; d < 8; d++) a = fmaf(u[s * 8 + d], wp[d * 160], a);
    up[idx] = a;
  }
  __syncthreads();

  for (int r = 0; r < 3; r++) {
    if (t < 36) {
      float m = bl[t * 10];
#pragma unroll
      for (int oc = 1; oc < 10; oc++) m = fmaxf(m, bl[t * 10 + oc]);
      float e[10]; float sum = 0.f;
#pragma unroll
      for (int oc = 0; oc < 10; oc++) { e[oc] = expf(bl[t * 10 + oc] - m); sum += e[oc]; }
      float inv = 1.f / sum;
#pragma unroll
      for (int oc = 0; oc < 10; oc++) cl[t * 10 + oc] = e[oc] * inv;
    }
    __syncthreads();
    if (t < 160) {
      const int oc = t >> 4;
      float a = 0.f;
#pragma unroll 1
      for (int s = 0; s < 36; s++) a = fmaf(cl[s * 10 + oc], up[s * 160 + t], a);
      sv[t] = a;
    }
    __syncthreads();
    if (t < 10) {
      float l2 = 0.f;
#pragma unroll
      for (int od = 0; od < 16; od++) { float v = sv[t * 16 + od]; l2 = fmaf(v, v, l2); }
      scale[t] = (l2 / (1.f + l2)) / (sqrtf(l2) + 1e-8f);
    }
    __syncthreads();
    if (t < 160) vv[t] = sv[t] * scale[t >> 4];
    __syncthreads();
    if (r < 2) {
      for (int idx = t; idx < 360; idx += 256) {
        int s = idx / 10, oc = idx - s * 10;
        float a = 0.f;
#pragma unroll
        for (int od = 0; od < 16; od++)
          a = fmaf(up[s * 160 + oc * 16 + od], vv[oc * 16 + od], a);
        bl[idx] += a;
      }
      __syncthreads();
    }
  }
  if (t < 160) vpart[(b * 32 + g) * 160 + t] = vv[t];
}

// ================== final: sum over groups + probs ==========================
__global__ __launch_bounds__(192) void final_k(
    const float* __restrict__ vpart, float* __restrict__ out) {
  __shared__ float v[160];
  const int b = blockIdx.x, t = threadIdx.x;
  if (t < 160) {
    float a = 0.f;
#pragma unroll 4
    for (int g = 0; g < 32; g++) a += vpart[(b * 32 + g) * 160 + t];
    v[t] = a;
    out[b * 160 + t] = a;
  }
  __syncthreads();
  if (t < 10) {
    float l2 = 0.f;
#pragma unroll
    for (int od = 0; od < 16; od++) { float x = v[t * 16 + od]; l2 = fmaf(x, x, l2); }
    out[40960 + b * 10 + t] = sqrtf(l2);
  }
}

// ===========================================================================
extern "C" void kernel_launch(void* const* d_in, const int* in_sizes, int n_in,
                              void* d_out, int out_size, void* d_ws, size_t ws_size,
                              hipStream_t stream) {
  const float* inp     = (const float*)d_in[0];
  const float* W1      = (const float*)d_in[1];
  const float* b1      = (const float*)d_in[2];
  const float* W2      = (const float*)d_in[3];
  const float* b2      = (const float*)d_in[4];
  const float* Wcaps   = (const float*)d_in[5];
  const float* b_route = (const float*)d_in[6];
  float* out = (float*)d_out;
  char* ws = (char*)d_ws;

  short* xhi = (short*)(ws + XHI_OFF);
  short* xlo = (short*)(ws + XLO_OFF);
  short* whi = (short*)(ws + WHI_OFF);
  short* wlo = (short*)(ws + WLO_OFF);
  float* y2  = (float*)(ws + Y2_OFF);
  float* vp  = (float*)(ws + VP_OFF);   // overlaps xhi (dead after conv2)

  (void)hipMemsetAsync(y2, 0, Y2_BYTES, stream);
  conv1_k <<<2048, 320, 0, stream>>>(inp, W1, b1, xhi, xlo);
  wtrans_k<<<256, 256, 0, stream>>>(W2, whi, wlo);
  conv2_k <<<256, 512, 0, stream>>>(xhi, xlo, whi, wlo, y2);
  caps_k  <<<8192, 256, 0, stream>>>(y2, b2, Wcaps, b_route, vp);
  final_k <<<256, 192, 0, stream>>>(vp, out);
}